// Round 6
// baseline (365.792 us; speedup 1.0000x reference)
//
#include <hip/hip_runtime.h>
#include <hip/hip_bf16.h>
#include <math.h>

// ---------------------------------------------------------------------------
// ScatterSelfAttention, R6:
//  - ONE persistent kernel (196 co-resident blocks, software grid barriers)
//    does: weight reorder/convert, x->bf16, CSR hist(+rank), 2-level scan,
//    scatter. 6 dispatches -> 1.
//  - gemm1/gemm2: bf16 MFMA, BN=128 tiles (x re-read 3x in bf16, not 6x f32)
//  - attn: exact R4 structure (4-pair unroll, VGPR 32, occ ~72%)
//  Graph: memset(bar) + prep_csr + gemm1 + attn + gemm2 = 5 nodes.
// ---------------------------------------------------------------------------

typedef __bf16 bf16x8 __attribute__((ext_vector_type(8)));
typedef float  f32x4  __attribute__((ext_vector_type(4)));

__device__ __forceinline__ ushort f32_to_bf16(float f) {
    uint u = __float_as_uint(f);
    u += 0x7FFF + ((u >> 16) & 1);          // RNE
    return (ushort)(u >> 16);
}
__device__ __forceinline__ uint pack_bf16x2(float a, float b) {
    return (uint)f32_to_bf16(a) | ((uint)f32_to_bf16(b) << 16);
}
__device__ __forceinline__ float bf_lo(uint w) { return __uint_as_float(w << 16); }
__device__ __forceinline__ float bf_hi(uint w) { return __uint_as_float(w & 0xFFFF0000u); }

// ---------------- GEMM: C[M,LDC](128-col tile) = A[M,128]bf16 @ Bt^T + bias --
template<int LDC, bool OUT_BF16>
__global__ __launch_bounds__(256) void gemm_mfma(
    const ushort* __restrict__ A, const ushort* __restrict__ Bt,
    const float* __restrict__ bias, void* __restrict__ Cv, int M)
{
    __shared__ uint4 As4[2048];   // 128 rows x 16 chunks, XOR-swizzled
    __shared__ uint4 Bs4[2048];   // 128 rows x 16 chunks, XOR-swizzled
    const int tid  = threadIdx.x;
    const int wave = tid >> 6;
    const int lane = tid & 63;
    const int qd   = lane >> 4;
    const int ln   = lane & 15;
    const int rowBase = blockIdx.x * 128;
    const int colBase = blockIdx.y * 128;

    const uint4* gA = (const uint4*)(A + (size_t)rowBase * 128);
    #pragma unroll
    for (int i = 0; i < 8; ++i) {
        int c  = tid + i * 256;
        int lc = (c & ~15) | ((c ^ (c >> 4)) & 15);
        As4[lc] = gA[c];
    }
    const uint4* gB = (const uint4*)(Bt + (size_t)colBase * 128);
    #pragma unroll
    for (int i = 0; i < 8; ++i) {
        int c  = tid + i * 256;
        int lc = (c & ~15) | ((c ^ (c >> 4)) & 15);
        Bs4[lc] = gB[c];
    }
    __syncthreads();

    f32x4 acc[2][8];
    #pragma unroll
    for (int i = 0; i < 2; ++i)
        #pragma unroll
        for (int j = 0; j < 8; ++j)
            acc[i][j] = (f32x4){0.f, 0.f, 0.f, 0.f};

    const int m0 = wave * 32;
    #pragma unroll
    for (int ks = 0; ks < 4; ++ks) {
        const int kc = ks * 4 + qd;
        bf16x8 a0 = *((const bf16x8*)&As4[(m0 +      ln) * 16 + (kc ^ ln)]);
        bf16x8 a1 = *((const bf16x8*)&As4[(m0 + 16 + ln) * 16 + (kc ^ ln)]);
        #pragma unroll
        for (int j = 0; j < 8; ++j) {
            bf16x8 b = *((const bf16x8*)&Bs4[(j * 16 + ln) * 16 + (kc ^ ln)]);
            acc[0][j] = __builtin_amdgcn_mfma_f32_16x16x32_bf16(a0, b, acc[0][j], 0, 0, 0);
            acc[1][j] = __builtin_amdgcn_mfma_f32_16x16x32_bf16(a1, b, acc[1][j], 0, 0, 0);
        }
    }

    // C/D layout: col = lane&15, row = (lane>>4)*4 + reg
    #pragma unroll
    for (int i = 0; i < 2; ++i) {
        int rbase = rowBase + m0 + i * 16 + qd * 4;
        #pragma unroll
        for (int j = 0; j < 8; ++j) {
            int colg = colBase + j * 16 + ln;
            float bv = bias[colg];
            #pragma unroll
            for (int r = 0; r < 4; ++r) {
                int gr = rbase + r;
                if (gr < M) {
                    float val = acc[i][j][r] + bv;
                    if (OUT_BF16)
                        ((ushort*)Cv)[(size_t)gr * LDC + colg] = f32_to_bf16(val);
                    else
                        ((float*)Cv)[(size_t)gr * LDC + colg] = val;
                }
            }
        }
    }
}

// ---------------- fused prep + CSR (persistent, grid barriers) --------------
__device__ __forceinline__ void grid_barrier(int* bar, int nblk, int phase)
{
    __syncthreads();
    if (threadIdx.x == 0) {
        __threadfence();                              // release (drain writes)
        atomicAdd(bar, 1);                            // device-scope
        const int target = nblk * phase;
        while (__hip_atomic_load(bar, __ATOMIC_RELAXED,
                                 __HIP_MEMORY_SCOPE_AGENT) < target)
            __builtin_amdgcn_s_sleep(1);
        __threadfence();                              // acquire (inv L1)
    }
    __syncthreads();
}

// Column order for Cb row (384 cols):
//   jj in [0,128)  -> q_jj
//   jj in [128,384): t = jj-128; chunk = t>>3 (= head*4+quad), pos = t&7
//                    col = head*16 + quad*4 + (pos&3); pos<4 -> K else V
__global__ __launch_bounds__(256) void prep_csr(
    const float* __restrict__ x, const int* __restrict__ dst,
    const float* __restrict__ Wq, const float* __restrict__ Wk,
    const float* __restrict__ Wv, const float* __restrict__ bq,
    const float* __restrict__ bk, const float* __restrict__ bv,
    const float* __restrict__ Wo,
    ushort* __restrict__ WcatT, float* __restrict__ bcatI, ushort* __restrict__ WoT,
    ushort* __restrict__ xb, int* __restrict__ cnt, int* __restrict__ rank,
    int* __restrict__ bsum, int* __restrict__ offp, int* __restrict__ eids,
    int* __restrict__ bar, int nblk, int N, int E, int Mpad)
{
    const int tid = threadIdx.x;
    const int gid = blockIdx.x * 256 + tid;
    const int GSZ = nblk * 256;
    __shared__ int sd[256];

    // ---- phase 0: zero cnt, build weights, convert x -> bf16 (zero-pad) ----
    if (gid < N) cnt[gid] = 0;

    const int WTOT = 384 * 128 + 384 + 128 * 128;
    for (int idx = gid; idx < WTOT; idx += GSZ) {
        if (idx < 384 * 128) {
            int jj = idx >> 7, k = idx & 127;
            const float* W; int c;
            if (jj < 128) { W = Wq; c = jj; }
            else {
                int t = jj - 128;
                int chunk = t >> 3, pos = t & 7;
                int h = chunk >> 2, g = chunk & 3;
                c = h * 16 + g * 4 + (pos & 3);
                W = (pos < 4) ? Wk : Wv;
            }
            WcatT[idx] = f32_to_bf16(W[k * 128 + c]);
        } else if (idx < 384 * 128 + 384) {
            int jj = idx - 384 * 128;
            float b;
            if (jj < 128) b = bq[jj];
            else {
                int t = jj - 128;
                int chunk = t >> 3, pos = t & 7;
                int h = chunk >> 2, g = chunk & 3;
                int c = h * 16 + g * 4 + (pos & 3);
                b = (pos < 4) ? bk[c] : bv[c];
            }
            bcatI[jj] = b;
        } else {
            int t = idx - (384 * 128 + 384);
            int n = t >> 7, k = t & 127;
            WoT[t] = f32_to_bf16(Wo[k * 128 + n]);
        }
    }

    for (int i = gid; i < Mpad * 32; i += GSZ) {       // one float4 -> ushort4
        int r = i >> 5;
        ushort4 o;
        if (r < N) {
            float4 v = ((const float4*)x)[i];
            o.x = f32_to_bf16(v.x); o.y = f32_to_bf16(v.y);
            o.z = f32_to_bf16(v.z); o.w = f32_to_bf16(v.w);
        } else {
            o.x = o.y = o.z = o.w = 0;
        }
        ((ushort4*)xb)[i] = o;
    }
    grid_barrier(bar, nblk, 1);

    // ---- phase 1: histogram + rank ----
    for (int e = gid; e < E; e += GSZ)
        rank[e] = atomicAdd(&cnt[dst[e]], 1);
    grid_barrier(bar, nblk, 2);

    // ---- phase 2: per-block inclusive scan of cnt (block b owns chunk b) ----
    int v = (gid < N) ? cnt[gid] : 0;
    sd[tid] = v;
    __syncthreads();
    #pragma unroll
    for (int o = 1; o < 256; o <<= 1) {
        int t = (tid >= o) ? sd[tid - o] : 0;
        __syncthreads();
        sd[tid] += t;
        __syncthreads();
    }
    int incl = sd[tid];
    if (tid == 255) bsum[blockIdx.x] = sd[255];
    grid_barrier(bar, nblk, 3);

    // ---- phase 3: block 0 exclusive-scans bsum[nblk] (nblk <= 256) ----
    if (blockIdx.x == 0) {
        int bv2 = (tid < nblk) ? bsum[tid] : 0;
        sd[tid] = bv2;
        __syncthreads();
        #pragma unroll
        for (int o = 1; o < 256; o <<= 1) {
            int t = (tid >= o) ? sd[tid - o] : 0;
            __syncthreads();
            sd[tid] += t;
            __syncthreads();
        }
        if (tid < nblk) bsum[tid] = sd[tid] - bv2;
    }
    grid_barrier(bar, nblk, 4);

    // ---- phase 4: offsets ----
    if (gid < N) offp[gid] = incl - v + bsum[blockIdx.x];
    if (gid == 0) offp[N] = E;
    grid_barrier(bar, nblk, 5);

    // ---- phase 5: scatter (pure writes, rank precomputed) ----
    for (int e = gid; e < E; e += GSZ)
        eids[offp[dst[e]] + rank[e]] = e;
}

// ---------------- attention (exact R4 structure) ----------------------------
// One wave per node, 4 nodes per 256-thread block. lane = e2*32 + c,
// c = head*4 + quad. One uint4 = (k quad | v quad) per lane per edge;
// parity halves process 2 edges per iteration. No LDS/barriers.
__global__ __launch_bounds__(256) void attn_kernel(
    const ushort* __restrict__ Cb, const int* __restrict__ off,
    const int* __restrict__ eids, const int* __restrict__ src_arr,
    const float* __restrict__ att_bias, float* __restrict__ logits_out,
    ushort* __restrict__ aggb, int N)
{
    const int wv   = threadIdx.x >> 6;
    const int lane = threadIdx.x & 63;
    const int node = blockIdx.x * 4 + wv;
    if (node >= N) return;
    const int e2 = lane >> 5;
    const int c  = lane & 31;      // head = c>>2, quad = c&3
    const int h  = c >> 2;

    uint2 qw = ((const uint2*)(Cb + (size_t)node * 384))[c];
    const float q0 = bf_lo(qw.x), q1 = bf_hi(qw.x);
    const float q2 = bf_lo(qw.y), q3 = bf_hi(qw.y);

    const int s = off[node];
    const int e = off[node + 1];
    const char* cb = (const char*)Cb;

    float l = 0.f, a0 = 0.f, a1 = 0.f, a2 = 0.f, a3 = 0.f;

    for (int b0 = s; b0 < e; b0 += 64) {
        const int cnt = min(64, e - b0);
        int gidx = b0 + ((lane < cnt) ? lane : (cnt - 1));
        int regEid = eids[gidx];
        uint regOff = (uint)src_arr[regEid] * 768u + 256u;   // byte off of kv region

        const int npairs = cnt >> 1;
        int t = 0;
        for (; t + 4 <= npairs; t += 4) {
            int  e4[4]; uint o4[4];
            uint4 w4[4]; float b4[4];
            #pragma unroll
            for (int j = 0; j < 4; ++j) {
                int idx = 2 * (t + j) + e2;
                e4[j] = __shfl(regEid, idx);
                o4[j] = __shfl(regOff, idx);
            }
            #pragma unroll
            for (int j = 0; j < 4; ++j) {
                w4[j] = *((const uint4*)(cb + o4[j]) + c);
                b4[j] = att_bias[e4[j] * 8 + h];
            }
            #pragma unroll
            for (int j = 0; j < 4; ++j) {
                uint4 w = w4[j];
                float p = q0 * bf_lo(w.x) + q1 * bf_hi(w.x)
                        + q2 * bf_lo(w.y) + q3 * bf_hi(w.y);
                p += __shfl_xor(p, 1);
                p += __shfl_xor(p, 2);
                float logit = p * 0.25f + b4[j];
                if ((c & 3) == 0) logits_out[e4[j] * 8 + h] = logit;
                float pe = __expf(logit);
                l += pe;
                a0 = fmaf(pe, bf_lo(w.z), a0); a1 = fmaf(pe, bf_hi(w.z), a1);
                a2 = fmaf(pe, bf_lo(w.w), a2); a3 = fmaf(pe, bf_hi(w.w), a3);
            }
        }
        for (; t < npairs; ++t) {
            int idx = 2 * t + e2;
            int  ei = __shfl(regEid, idx);
            uint of = __shfl(regOff, idx);
            uint4 w = *((const uint4*)(cb + of) + c);
            float bb = att_bias[ei * 8 + h];
            float p = q0 * bf_lo(w.x) + q1 * bf_hi(w.x)
                    + q2 * bf_lo(w.y) + q3 * bf_hi(w.y);
            p += __shfl_xor(p, 1);
            p += __shfl_xor(p, 2);
            float logit = p * 0.25f + bb;
            if ((c & 3) == 0) logits_out[ei * 8 + h] = logit;
            float pe = __expf(logit);
            l += pe;
            a0 = fmaf(pe, bf_lo(w.z), a0); a1 = fmaf(pe, bf_hi(w.z), a1);
            a2 = fmaf(pe, bf_lo(w.w), a2); a3 = fmaf(pe, bf_hi(w.w), a3);
        }
        if (cnt & 1) {                        // odd tail: parity 0 contributes
            int idx = cnt - 1;
            int  ei = __shfl(regEid, idx);
            uint of = __shfl(regOff, idx);
            uint4 w = *((const uint4*)(cb + of) + c);
            float bb = att_bias[ei * 8 + h];
            float p = q0 * bf_lo(w.x) + q1 * bf_hi(w.x)
                    + q2 * bf_lo(w.y) + q3 * bf_hi(w.y);
            p += __shfl_xor(p, 1);
            p += __shfl_xor(p, 2);
            float logit = p * 0.25f + bb;
            if ((c & 3) == 0 && e2 == 0) logits_out[ei * 8 + h] = logit;
            float pe = (e2 == 0) ? __expf(logit) : 0.f;
            l += pe;
            a0 = fmaf(pe, bf_lo(w.z), a0); a1 = fmaf(pe, bf_hi(w.z), a1);
            a2 = fmaf(pe, bf_lo(w.w), a2); a3 = fmaf(pe, bf_hi(w.w), a3);
        }
    }

    l  += __shfl_xor(l, 32);
    a0 += __shfl_xor(a0, 32);
    a1 += __shfl_xor(a1, 32);
    a2 += __shfl_xor(a2, 32);
    a3 += __shfl_xor(a3, 32);
    float inv = (l > 0.f) ? (1.f / l) : 0.f;
    if (e2 == 0) {
        uint2 o;
        o.x = pack_bf16x2(a0 * inv, a1 * inv);
        o.y = pack_bf16x2(a2 * inv, a3 * inv);
        ((uint2*)(aggb + (size_t)node * 128))[c] = o;   // cols 4c..4c+3
    }
}

extern "C" void kernel_launch(void* const* d_in, const int* in_sizes, int n_in,
                              void* d_out, int out_size, void* d_ws, size_t ws_size,
                              hipStream_t stream)
{
    const float* x        = (const float*)d_in[0];
    const int*   ei       = (const int*)d_in[1];   // [2,E]: dst row then src row
    const float* att_bias = (const float*)d_in[2];
    const float* Wq = (const float*)d_in[3];  const float* bq = (const float*)d_in[4];
    const float* Wk = (const float*)d_in[5];  const float* bk = (const float*)d_in[6];
    const float* Wv = (const float*)d_in[7];  const float* bv = (const float*)d_in[8];
    const float* Wo = (const float*)d_in[9];  const float* bo = (const float*)d_in[10];

    const int N = in_sizes[0] / 128;
    const int E = in_sizes[1] / 2;

    float* out    = (float*)d_out;               // [N,128]
    float* logits = out + (size_t)N * 128;       // [E,8]

    char* ws = (char*)d_ws;
    size_t o = 0;
    auto alloc = [&](size_t bytes) -> char* {
        char* p = ws + o;
        o = (o + bytes + 255) & ~(size_t)255;
        return p;
    };
    const int Mpad = ((N + 127) / 128) * 128;
    ushort* Cb    = (ushort*)alloc((size_t)N * 384 * 2);   // q | packed kv chunks
    ushort* aggb  = (ushort*)alloc((size_t)Mpad * 128 * 2);
    ushort* xb    = (ushort*)alloc((size_t)Mpad * 128 * 2);
    ushort* WcatT = (ushort*)alloc((size_t)384 * 128 * 2);
    float*  bcatI = (float*)alloc(384 * 4);
    ushort* WoT   = (ushort*)alloc((size_t)128 * 128 * 2);
    int*    cnt   = (int*)alloc((size_t)N * 4);
    int*    rank  = (int*)alloc((size_t)E * 4);
    const int NBLK = (N + 255) / 256;            // 196 <= 256: co-resident
    int*    bsum  = (int*)alloc((size_t)NBLK * 4);
    int*    offp  = (int*)alloc((size_t)(N + 1) * 4);
    int*    eidsp = (int*)alloc((size_t)E * 4);
    int*    bar   = (int*)alloc(256);

    const int MB = (N + 127) / 128;

    hipMemsetAsync(bar, 0, 4, stream);

    prep_csr<<<NBLK, 256, 0, stream>>>(x, ei, Wq, Wk, Wv, bq, bk, bv, Wo,
                                       WcatT, bcatI, WoT, xb, cnt, rank,
                                       bsum, offp, eidsp, bar, NBLK, N, E, Mpad);

    dim3 g1(MB, 3);
    gemm_mfma<384, true><<<g1, 256, 0, stream>>>(xb, WcatT, bcatI, Cb, N);

    attn_kernel<<<(N + 3) / 4, 256, 0, stream>>>(Cb, offp, eidsp, ei + E, att_bias,
                                                 logits, aggb, N);

    dim3 g2(MB, 1);
    gemm_mfma<128, false><<<g2, 256, 0, stream>>>(aggb, WoT, bo, out, N);
}

// Round 7
// 281.509 us; speedup vs baseline: 1.2994x; 1.2994x over previous
//
#include <hip/hip_runtime.h>
#include <hip/hip_bf16.h>
#include <math.h>

// ---------------------------------------------------------------------------
// ScatterSelfAttention, R7:
//  - revert persistent fusion (R6 FAILED: 196-block cap -> 8.8% occupancy)
//  - GEMM: swapped-operand MFMA (mfma(b,a)) transposes C/D so each lane owns
//    4 consecutive columns -> uint2/float4 stores (16 instead of 64 stores)
//  - prep: one grid-stride kernel (cnt=0 + weight reorder + x->bf16)
//  - CSR: hist(+rank) -> scan_block -> scan_finish(top merged) -> scatter
//    writing int2(src,eid) pairs (attn loses the random src gather)
//  - attn: exact R4 structure (4-pair unroll, 32 lanes/edge, no LDS)
//  8 graph nodes: prep, gemm1, hist, scan_block, scan_finish, scatter,
//  attn, gemm2.
// ---------------------------------------------------------------------------

typedef __bf16 bf16x8 __attribute__((ext_vector_type(8)));
typedef float  f32x4  __attribute__((ext_vector_type(4)));

__device__ __forceinline__ ushort f32_to_bf16(float f) {
    uint u = __float_as_uint(f);
    u += 0x7FFF + ((u >> 16) & 1);          // RNE
    return (ushort)(u >> 16);
}
__device__ __forceinline__ uint pack_bf16x2(float a, float b) {
    return (uint)f32_to_bf16(a) | ((uint)f32_to_bf16(b) << 16);
}
__device__ __forceinline__ float bf_lo(uint w) { return __uint_as_float(w << 16); }
__device__ __forceinline__ float bf_hi(uint w) { return __uint_as_float(w & 0xFFFF0000u); }

// C[M,LDC](128-col tile) = A[M,128]bf16 @ Bt[LDC,128]^T + bias.
// mfma(b,a): first operand's index -> (quad,reg), second's -> lane&15.
// So lane ln owns row (rowBase+wave*32+i*16+ln), cols (colBase+j*16+qd*4..+3).
template<int LDC, bool OUT_BF16>
__global__ __launch_bounds__(256) void gemm_mfma(
    const ushort* __restrict__ A, const ushort* __restrict__ Bt,
    const float* __restrict__ bias, void* __restrict__ Cv, int M)
{
    __shared__ uint4 As4[2048];   // 128 rows x 16 chunks, XOR-swizzled
    __shared__ uint4 Bs4[2048];
    const int tid  = threadIdx.x;
    const int wave = tid >> 6;
    const int lane = tid & 63;
    const int qd   = lane >> 4;
    const int ln   = lane & 15;
    const int rowBase = blockIdx.x * 128;
    const int colBase = blockIdx.y * 128;

    const uint4* gA = (const uint4*)(A + (size_t)rowBase * 128);
    #pragma unroll
    for (int i = 0; i < 8; ++i) {
        int c  = tid + i * 256;
        int lc = (c & ~15) | ((c ^ (c >> 4)) & 15);
        As4[lc] = gA[c];
    }
    const uint4* gB = (const uint4*)(Bt + (size_t)colBase * 128);
    #pragma unroll
    for (int i = 0; i < 8; ++i) {
        int c  = tid + i * 256;
        int lc = (c & ~15) | ((c ^ (c >> 4)) & 15);
        Bs4[lc] = gB[c];
    }
    __syncthreads();

    f32x4 acc[2][8];
    #pragma unroll
    for (int i = 0; i < 2; ++i)
        #pragma unroll
        for (int j = 0; j < 8; ++j)
            acc[i][j] = (f32x4){0.f, 0.f, 0.f, 0.f};

    const int m0 = wave * 32;
    #pragma unroll
    for (int ks = 0; ks < 4; ++ks) {
        const int kc = ks * 4 + qd;
        bf16x8 a0 = *((const bf16x8*)&As4[(m0 +      ln) * 16 + (kc ^ ln)]);
        bf16x8 a1 = *((const bf16x8*)&As4[(m0 + 16 + ln) * 16 + (kc ^ ln)]);
        #pragma unroll
        for (int j = 0; j < 8; ++j) {
            bf16x8 b = *((const bf16x8*)&Bs4[(j * 16 + ln) * 16 + (kc ^ ln)]);
            acc[0][j] = __builtin_amdgcn_mfma_f32_16x16x32_bf16(b, a0, acc[0][j], 0, 0, 0);
            acc[1][j] = __builtin_amdgcn_mfma_f32_16x16x32_bf16(b, a1, acc[1][j], 0, 0, 0);
        }
    }

    #pragma unroll
    for (int i = 0; i < 2; ++i) {
        int gr = rowBase + m0 + i * 16 + ln;
        if (gr < M) {
            #pragma unroll
            for (int j = 0; j < 8; ++j) {
                int coln = colBase + j * 16 + qd * 4;
                float4 b4 = *((const float4*)(bias + coln));
                float v0 = acc[i][j][0] + b4.x;
                float v1 = acc[i][j][1] + b4.y;
                float v2 = acc[i][j][2] + b4.z;
                float v3 = acc[i][j][3] + b4.w;
                if (OUT_BF16) {
                    uint2 o;
                    o.x = pack_bf16x2(v0, v1);
                    o.y = pack_bf16x2(v2, v3);
                    *((uint2*)((ushort*)Cv + (size_t)gr * LDC + coln)) = o;
                } else {
                    float4 o = make_float4(v0, v1, v2, v3);
                    *((float4*)((float*)Cv + (size_t)gr * LDC + coln)) = o;
                }
            }
        }
    }
}

// Grid-stride prep: zero cnt, build WcatT/bcatI/WoT, convert x -> bf16 (pad).
// Column order for Cb row (384 cols):
//   jj in [0,128)  -> q_jj
//   jj in [128,384): t = jj-128; chunk = t>>3 (= head*4+quad), pos = t&7
//                    col = head*16 + quad*4 + (pos&3); pos<4 -> K else V
__global__ __launch_bounds__(256) void prep_kernel(
    const float* __restrict__ x,
    const float* __restrict__ Wq, const float* __restrict__ Wk,
    const float* __restrict__ Wv, const float* __restrict__ bq,
    const float* __restrict__ bk, const float* __restrict__ bv,
    const float* __restrict__ Wo,
    ushort* __restrict__ WcatT, float* __restrict__ bcatI, ushort* __restrict__ WoT,
    ushort* __restrict__ xb, int* __restrict__ cnt, int N, int Mpad, int GSZ)
{
    const int gid = blockIdx.x * 256 + threadIdx.x;

    for (int i = gid; i < N; i += GSZ) cnt[i] = 0;

    const int WTOT = 384 * 128 + 384 + 128 * 128;
    for (int idx = gid; idx < WTOT; idx += GSZ) {
        if (idx < 384 * 128) {
            int jj = idx >> 7, k = idx & 127;
            const float* W; int c;
            if (jj < 128) { W = Wq; c = jj; }
            else {
                int t = jj - 128;
                int chunk = t >> 3, pos = t & 7;
                int h = chunk >> 2, g = chunk & 3;
                c = h * 16 + g * 4 + (pos & 3);
                W = (pos < 4) ? Wk : Wv;
            }
            WcatT[idx] = f32_to_bf16(W[k * 128 + c]);
        } else if (idx < 384 * 128 + 384) {
            int jj = idx - 384 * 128;
            float b;
            if (jj < 128) b = bq[jj];
            else {
                int t = jj - 128;
                int chunk = t >> 3, pos = t & 7;
                int h = chunk >> 2, g = chunk & 3;
                int c = h * 16 + g * 4 + (pos & 3);
                b = (pos < 4) ? bk[c] : bv[c];
            }
            bcatI[jj] = b;
        } else {
            int t = idx - (384 * 128 + 384);
            int n = t >> 7, k = t & 127;
            WoT[t] = f32_to_bf16(Wo[k * 128 + n]);
        }
    }

    for (int i = gid; i < Mpad * 32; i += GSZ) {       // float4 -> ushort4
        int r = i >> 5;
        ushort4 o;
        if (r < N) {
            float4 v = ((const float4*)x)[i];
            o.x = f32_to_bf16(v.x); o.y = f32_to_bf16(v.y);
            o.z = f32_to_bf16(v.z); o.w = f32_to_bf16(v.w);
        } else {
            o.x = o.y = o.z = o.w = 0;
        }
        ((ushort4*)xb)[i] = o;
    }
}

__global__ void hist_kernel(const int* __restrict__ dst, int* __restrict__ cnt,
                            int* __restrict__ rank, int E)
{
    int e = blockIdx.x * 256 + threadIdx.x;
    if (e < E) rank[e] = atomicAdd(&cnt[dst[e]], 1);
}

__global__ __launch_bounds__(256) void scan_block(const int* __restrict__ cnt,
                                                  int* __restrict__ incl,
                                                  int* __restrict__ bsum, int N)
{
    __shared__ int sd[256];
    int tid = threadIdx.x;
    int i = blockIdx.x * 256 + tid;
    int v = (i < N) ? cnt[i] : 0;
    sd[tid] = v;
    __syncthreads();
    #pragma unroll
    for (int o = 1; o < 256; o <<= 1) {
        int t = (tid >= o) ? sd[tid - o] : 0;
        __syncthreads();
        sd[tid] += t;
        __syncthreads();
    }
    if (i < N) incl[i] = sd[tid];
    if (tid == 255) bsum[blockIdx.x] = sd[255];
}

// Each block re-scans bsum (nblk<=256) in LDS, takes its exclusive prefix,
// and finishes the offsets. Replaces scan_top + scan_finish.
__global__ __launch_bounds__(256) void scan_finish(
    const int* __restrict__ cnt, const int* __restrict__ incl,
    const int* __restrict__ bsum, int* __restrict__ offp,
    int N, int E, int nblk)
{
    __shared__ int sd[256];
    __shared__ int pfx;
    int tid = threadIdx.x;
    int v = (tid < nblk) ? bsum[tid] : 0;
    sd[tid] = v;
    __syncthreads();
    #pragma unroll
    for (int o = 1; o < 256; o <<= 1) {
        int t = (tid >= o) ? sd[tid - o] : 0;
        __syncthreads();
        sd[tid] += t;
        __syncthreads();
    }
    if (tid == blockIdx.x) pfx = sd[tid] - v;   // exclusive prefix of this block
    __syncthreads();
    int i = blockIdx.x * 256 + tid;
    if (i < N) offp[i] = incl[i] - cnt[i] + pfx;
    if (i == 0) offp[N] = E;
}

// pairs[slot] = (src, eid): attn reads one coalesced int2 per edge slot.
__global__ void scatter_kernel(const int* __restrict__ dst, const int* __restrict__ srcs,
                               const int* __restrict__ rank, const int* __restrict__ offp,
                               int2* __restrict__ pairs, int E)
{
    int e = blockIdx.x * 256 + threadIdx.x;
    if (e < E) pairs[offp[dst[e]] + rank[e]] = make_int2(srcs[e], e);
}

// One wave per node, 4 nodes per 256-thread block. lane = e2*32 + c,
// c = head*4 + quad. One uint4 = (k quad | v quad) per lane per edge;
// parity halves process 2 edges per iteration. No LDS/barriers.
__global__ __launch_bounds__(256) void attn_kernel(
    const ushort* __restrict__ Cb, const int* __restrict__ off,
    const int2* __restrict__ pairs, const float* __restrict__ att_bias,
    float* __restrict__ logits_out, ushort* __restrict__ aggb, int N)
{
    const int wv   = threadIdx.x >> 6;
    const int lane = threadIdx.x & 63;
    const int node = blockIdx.x * 4 + wv;
    if (node >= N) return;
    const int e2 = lane >> 5;
    const int c  = lane & 31;      // head = c>>2, quad = c&3
    const int h  = c >> 2;

    uint2 qw = ((const uint2*)(Cb + (size_t)node * 384))[c];
    const float q0 = bf_lo(qw.x), q1 = bf_hi(qw.x);
    const float q2 = bf_lo(qw.y), q3 = bf_hi(qw.y);

    const int s = off[node];
    const int e = off[node + 1];
    const char* cb = (const char*)Cb;

    float l = 0.f, a0 = 0.f, a1 = 0.f, a2 = 0.f, a3 = 0.f;

    for (int b0 = s; b0 < e; b0 += 64) {
        const int cnt = min(64, e - b0);
        int gidx = b0 + ((lane < cnt) ? lane : (cnt - 1));
        int2 se = pairs[gidx];                         // coalesced (src, eid)
        int  regEid = se.y;
        uint regOff = (uint)se.x * 768u + 256u;        // byte off of kv region

        const int npairs = cnt >> 1;
        int t = 0;
        for (; t + 4 <= npairs; t += 4) {
            int  e4[4]; uint o4[4];
            uint4 w4[4]; float b4[4];
            #pragma unroll
            for (int j = 0; j < 4; ++j) {
                int idx = 2 * (t + j) + e2;
                e4[j] = __shfl(regEid, idx);
                o4[j] = __shfl(regOff, idx);
            }
            #pragma unroll
            for (int j = 0; j < 4; ++j) {
                w4[j] = *((const uint4*)(cb + o4[j]) + c);
                b4[j] = att_bias[e4[j] * 8 + h];
            }
            #pragma unroll
            for (int j = 0; j < 4; ++j) {
                uint4 w = w4[j];
                float p = q0 * bf_lo(w.x) + q1 * bf_hi(w.x)
                        + q2 * bf_lo(w.y) + q3 * bf_hi(w.y);
                p += __shfl_xor(p, 1);
                p += __shfl_xor(p, 2);
                float logit = p * 0.25f + b4[j];
                if ((c & 3) == 0) logits_out[e4[j] * 8 + h] = logit;
                float pe = __expf(logit);
                l += pe;
                a0 = fmaf(pe, bf_lo(w.z), a0); a1 = fmaf(pe, bf_hi(w.z), a1);
                a2 = fmaf(pe, bf_lo(w.w), a2); a3 = fmaf(pe, bf_hi(w.w), a3);
            }
        }
        for (; t < npairs; ++t) {
            int idx = 2 * t + e2;
            int  ei = __shfl(regEid, idx);
            uint of = __shfl(regOff, idx);
            uint4 w = *((const uint4*)(cb + of) + c);
            float bb = att_bias[ei * 8 + h];
            float p = q0 * bf_lo(w.x) + q1 * bf_hi(w.x)
                    + q2 * bf_lo(w.y) + q3 * bf_hi(w.y);
            p += __shfl_xor(p, 1);
            p += __shfl_xor(p, 2);
            float logit = p * 0.25f + bb;
            if ((c & 3) == 0) logits_out[ei * 8 + h] = logit;
            float pe = __expf(logit);
            l += pe;
            a0 = fmaf(pe, bf_lo(w.z), a0); a1 = fmaf(pe, bf_hi(w.z), a1);
            a2 = fmaf(pe, bf_lo(w.w), a2); a3 = fmaf(pe, bf_hi(w.w), a3);
        }
        if (cnt & 1) {                        // odd tail: parity 0 contributes
            int idx = cnt - 1;
            int  ei = __shfl(regEid, idx);
            uint of = __shfl(regOff, idx);
            uint4 w = *((const uint4*)(cb + of) + c);
            float bb = att_bias[ei * 8 + h];
            float p = q0 * bf_lo(w.x) + q1 * bf_hi(w.x)
                    + q2 * bf_lo(w.y) + q3 * bf_hi(w.y);
            p += __shfl_xor(p, 1);
            p += __shfl_xor(p, 2);
            float logit = p * 0.25f + bb;
            if ((c & 3) == 0 && e2 == 0) logits_out[ei * 8 + h] = logit;
            float pe = (e2 == 0) ? __expf(logit) : 0.f;
            l += pe;
            a0 = fmaf(pe, bf_lo(w.z), a0); a1 = fmaf(pe, bf_hi(w.z), a1);
            a2 = fmaf(pe, bf_lo(w.w), a2); a3 = fmaf(pe, bf_hi(w.w), a3);
        }
    }

    l  += __shfl_xor(l, 32);
    a0 += __shfl_xor(a0, 32);
    a1 += __shfl_xor(a1, 32);
    a2 += __shfl_xor(a2, 32);
    a3 += __shfl_xor(a3, 32);
    float inv = (l > 0.f) ? (1.f / l) : 0.f;
    if (e2 == 0) {
        uint2 o;
        o.x = pack_bf16x2(a0 * inv, a1 * inv);
        o.y = pack_bf16x2(a2 * inv, a3 * inv);
        ((uint2*)(aggb + (size_t)node * 128))[c] = o;   // cols 4c..4c+3
    }
}

extern "C" void kernel_launch(void* const* d_in, const int* in_sizes, int n_in,
                              void* d_out, int out_size, void* d_ws, size_t ws_size,
                              hipStream_t stream)
{
    const float* x        = (const float*)d_in[0];
    const int*   ei       = (const int*)d_in[1];   // [2,E]: dst row then src row
    const float* att_bias = (const float*)d_in[2];
    const float* Wq = (const float*)d_in[3];  const float* bq = (const float*)d_in[4];
    const float* Wk = (const float*)d_in[5];  const float* bk = (const float*)d_in[6];
    const float* Wv = (const float*)d_in[7];  const float* bv = (const float*)d_in[8];
    const float* Wo = (const float*)d_in[9];  const float* bo = (const float*)d_in[10];

    const int N = in_sizes[0] / 128;
    const int E = in_sizes[1] / 2;

    float* out    = (float*)d_out;               // [N,128]
    float* logits = out + (size_t)N * 128;       // [E,8]

    char* ws = (char*)d_ws;
    size_t o = 0;
    auto alloc = [&](size_t bytes) -> char* {
        char* p = ws + o;
        o = (o + bytes + 255) & ~(size_t)255;
        return p;
    };
    const int Mpad = ((N + 127) / 128) * 128;
    ushort* Cb    = (ushort*)alloc((size_t)N * 384 * 2);   // q | packed kv chunks
    ushort* aggb  = (ushort*)alloc((size_t)Mpad * 128 * 2);
    ushort* xb    = (ushort*)alloc((size_t)Mpad * 128 * 2);
    ushort* WcatT = (ushort*)alloc((size_t)384 * 128 * 2);
    float*  bcatI = (float*)alloc(384 * 4);
    ushort* WoT   = (ushort*)alloc((size_t)128 * 128 * 2);
    int*    cnt   = (int*)alloc((size_t)N * 4);
    int*    incl  = (int*)alloc((size_t)N * 4);
    int*    rank  = (int*)alloc((size_t)E * 4);
    const int NBLK = (N + 255) / 256;            // 196
    int*    bsum  = (int*)alloc((size_t)NBLK * 4);
    int*    offp  = (int*)alloc((size_t)(N + 1) * 4);
    int2*   pairs = (int2*)alloc((size_t)E * 8);

    const int MB  = (N + 127) / 128;
    const int nbE = (E + 255) / 256;

    const int PREP_BLOCKS = 1024;
    prep_kernel<<<PREP_BLOCKS, 256, 0, stream>>>(
        x, Wq, Wk, Wv, bq, bk, bv, Wo, WcatT, bcatI, WoT, xb, cnt,
        N, Mpad, PREP_BLOCKS * 256);

    dim3 g1(MB, 3);
    gemm_mfma<384, true><<<g1, 256, 0, stream>>>(xb, WcatT, bcatI, Cb, N);

    hist_kernel<<<nbE, 256, 0, stream>>>(ei, cnt, rank, E);
    scan_block<<<NBLK, 256, 0, stream>>>(cnt, incl, bsum, N);
    scan_finish<<<NBLK, 256, 0, stream>>>(cnt, incl, bsum, offp, N, E, NBLK);
    scatter_kernel<<<nbE, 256, 0, stream>>>(ei, ei + E, rank, offp, pairs, E);

    attn_kernel<<<(N + 3) / 4, 256, 0, stream>>>(Cb, offp, pairs, att_bias,
                                                 logits, aggb, N);

    dim3 g2(MB, 1);
    gemm_mfma<128, false><<<g2, 256, 0, stream>>>(aggb, WoT, bo, out, N);
}